// Round 1
// baseline (264.997 us; speedup 1.0000x reference)
//
#include <hip/hip_runtime.h>
#include <hip/hip_bf16.h>
#include <math.h>

#define B_ 2
#define S_ 2048
#define D_ 1024
#define H_ 16
#define DK_ 64

typedef __bf16 bf16_t;
typedef bf16_t bf16x8 __attribute__((ext_vector_type(8)));
typedef bf16_t bf16x4 __attribute__((ext_vector_type(4)));
typedef float f32x4 __attribute__((ext_vector_type(4)));

// ---------------- cast fp32 -> bf16, vectorized ----------------
__global__ __launch_bounds__(256) void cast_bf16_vec(const float* __restrict__ in,
                                                     bf16_t* __restrict__ out, int n4) {
  int i = blockIdx.x * 256 + threadIdx.x;
  if (i >= n4) return;
  float4 f = reinterpret_cast<const float4*>(in)[i];
  bf16x4 o;
  o[0] = (bf16_t)f.x; o[1] = (bf16_t)f.y; o[2] = (bf16_t)f.z; o[3] = (bf16_t)f.w;
  reinterpret_cast<bf16x4*>(out)[i] = o;
}

// ---------------- GEMM: C[M,N] = A[M,K] * W[N,K]^T (bf16 in, fp32 acc) ------
// 128x128 tile, BK=64, 256 threads (4 waves, 2x2), each wave 64x64 out.
template <bool OUT_F32>
__global__ __launch_bounds__(256) void gemm_bt(const bf16_t* __restrict__ A,
                                               const bf16_t* __restrict__ W,
                                               void* __restrict__ Cout,
                                               int Ndim, int Kdim) {
  __shared__ __attribute__((aligned(16))) bf16_t As[128][72];
  __shared__ __attribute__((aligned(16))) bf16_t Bs[128][72];
  const int bm = blockIdx.x * 128;
  const int bn = blockIdx.y * 128;
  const int tid = threadIdx.x;
  const int lane = tid & 63;
  const int w = tid >> 6;
  const int wr = w >> 1, wc = w & 1;

  f32x4 acc[4][4];
  for (int m = 0; m < 4; ++m)
    for (int n = 0; n < 4; ++n) acc[m][n] = (f32x4){0.f, 0.f, 0.f, 0.f};

  for (int k0 = 0; k0 < Kdim; k0 += 64) {
    __syncthreads();
    for (int v = tid; v < 1024; v += 256) {
      int r = v >> 3, c = (v & 7) << 3;
      *reinterpret_cast<bf16x8*>(&As[r][c]) =
          *reinterpret_cast<const bf16x8*>(&A[(size_t)(bm + r) * Kdim + k0 + c]);
      *reinterpret_cast<bf16x8*>(&Bs[r][c]) =
          *reinterpret_cast<const bf16x8*>(&W[(size_t)(bn + r) * Kdim + k0 + c]);
    }
    __syncthreads();
#pragma unroll
    for (int t = 0; t < 2; ++t) {
      const int kk = t * 32 + ((lane >> 4) << 3);
      bf16x8 af[4], bfr[4];
#pragma unroll
      for (int m = 0; m < 4; ++m)
        af[m] = *reinterpret_cast<const bf16x8*>(&As[wr * 64 + m * 16 + (lane & 15)][kk]);
#pragma unroll
      for (int n = 0; n < 4; ++n)
        bfr[n] = *reinterpret_cast<const bf16x8*>(&Bs[wc * 64 + n * 16 + (lane & 15)][kk]);
#pragma unroll
      for (int m = 0; m < 4; ++m)
#pragma unroll
        for (int n = 0; n < 4; ++n)
          acc[m][n] = __builtin_amdgcn_mfma_f32_16x16x32_bf16(af[m], bfr[n], acc[m][n], 0, 0, 0);
    }
  }

  const int rg = (lane >> 4) << 2, c0 = lane & 15;
#pragma unroll
  for (int m = 0; m < 4; ++m)
#pragma unroll
    for (int n = 0; n < 4; ++n) {
      int r = bm + wr * 64 + m * 16 + rg;
      int c = bn + wc * 64 + n * 16 + c0;
#pragma unroll
      for (int i = 0; i < 4; ++i) {
        if (OUT_F32)
          reinterpret_cast<float*>(Cout)[(size_t)(r + i) * Ndim + c] = acc[m][n][i];
        else
          reinterpret_cast<bf16_t*>(Cout)[(size_t)(r + i) * Ndim + c] = (bf16_t)acc[m][n][i];
      }
    }
}

// ---------------- RoPE (interleaved pairs) + head reorder -------------------
// QKV: (B*S, 3072) bf16 ; out Qr/Kr/Vr: (B,H,S,64) bf16
__global__ __launch_bounds__(256) void rope_reorder(const bf16_t* __restrict__ QKV,
                                                    const int* __restrict__ posids,
                                                    bf16_t* __restrict__ Qr,
                                                    bf16_t* __restrict__ Kr,
                                                    bf16_t* __restrict__ Vr) {
  int idx = blockIdx.x * 256 + threadIdx.x;  // (b,s,h,i) i in [0,32)
  int i = idx & 31;
  int h = (idx >> 5) & (H_ - 1);
  int s = (idx >> 9) & (S_ - 1);
  int b = idx >> 20;
  int p = posids[b * S_ + s];
  // inv_freq = 10000^(-2i/64) = exp(-2i * ln(10000)/64)
  float ang = (float)p * __expf(-(float)(2 * i) * (9.210340371976184f / 64.0f));
  float cs = cosf(ang), sn = sinf(ang);
  size_t inbase = ((size_t)(b * S_ + s)) * 3072 + h * 64 + 2 * i;
  float q0 = (float)QKV[inbase],        q1 = (float)QKV[inbase + 1];
  float k0 = (float)QKV[inbase + 1024], k1 = (float)QKV[inbase + 1025];
  size_t obase = ((size_t)((b * H_ + h) * S_ + s)) * 64 + 2 * i;
  Qr[obase]     = (bf16_t)(cs * q0 - sn * q1);
  Qr[obase + 1] = (bf16_t)(sn * q0 + cs * q1);
  Kr[obase]     = (bf16_t)(cs * k0 - sn * k1);
  Kr[obase + 1] = (bf16_t)(sn * k0 + cs * k1);
  Vr[obase]     = QKV[inbase + 2048];
  Vr[obase + 1] = QKV[inbase + 2049];
}

// ---------------- causal flash attention ------------------------------------
// grid: (S/64, B*H). 4 waves; wave w owns Q rows [qb+16w, qb+16w+16).
__global__ __launch_bounds__(256) void attn_kernel(const bf16_t* __restrict__ Qr,
                                                   const bf16_t* __restrict__ Kr,
                                                   const bf16_t* __restrict__ Vr,
                                                   bf16_t* __restrict__ AO) {
  const int qb = blockIdx.x * 64;
  const int bh = blockIdx.y;
  const int b = bh >> 4, h = bh & 15;
  const bf16_t* Qp = Qr + (size_t)bh * S_ * 64;
  const bf16_t* Kp = Kr + (size_t)bh * S_ * 64;
  const bf16_t* Vp = Vr + (size_t)bh * S_ * 64;
  const int tid = threadIdx.x, lane = tid & 63, w = tid >> 6;

  __shared__ __attribute__((aligned(16))) bf16_t Ksm[64][72];
  __shared__ __attribute__((aligned(16))) bf16_t Vt[64][72];   // Vt[dk][kv]
  __shared__ __attribute__((aligned(16))) bf16_t Psm[4][16][72];

  // Q fragments (A-operand), held in registers for the whole kernel
  bf16x8 qf[2];
  {
    int qrow = qb + w * 16 + (lane & 15);
#pragma unroll
    for (int t = 0; t < 2; ++t)
      qf[t] = *reinterpret_cast<const bf16x8*>(
          &Qp[(size_t)qrow * 64 + t * 32 + ((lane >> 4) << 3)]);
  }

  f32x4 o[4];
  for (int n = 0; n < 4; ++n) o[n] = (f32x4){0.f, 0.f, 0.f, 0.f};
  float mrow[4] = {-1e30f, -1e30f, -1e30f, -1e30f};
  float lrow[4] = {0.f, 0.f, 0.f, 0.f};

  const int ktmax = qb >> 6;
  for (int kt = 0; kt <= ktmax; ++kt) {
    __syncthreads();
    // stage K tile row-major; V tile transposed (Vt[dk][kv])
    for (int v = tid; v < 512; v += 256) {
      int r = v >> 3, c = (v & 7) << 3;
      *reinterpret_cast<bf16x8*>(&Ksm[r][c]) =
          *reinterpret_cast<const bf16x8*>(&Kp[(size_t)(kt * 64 + r) * 64 + c]);
      bf16x8 vv = *reinterpret_cast<const bf16x8*>(&Vp[(size_t)(kt * 64 + r) * 64 + c]);
#pragma unroll
      for (int j = 0; j < 8; ++j) Vt[c + j][r] = vv[j];
    }
    __syncthreads();

    // scores S = Q K^T (wave strip 16 x 64)
    f32x4 sacc[4];
    for (int n = 0; n < 4; ++n) sacc[n] = (f32x4){0.f, 0.f, 0.f, 0.f};
#pragma unroll
    for (int t = 0; t < 2; ++t) {
      const int kk = t * 32 + ((lane >> 4) << 3);
#pragma unroll
      for (int n = 0; n < 4; ++n) {
        bf16x8 kfr = *reinterpret_cast<const bf16x8*>(&Ksm[n * 16 + (lane & 15)][kk]);
        sacc[n] = __builtin_amdgcn_mfma_f32_16x16x32_bf16(qf[t], kfr, sacc[n], 0, 0, 0);
      }
    }

    // scale + causal mask (only diagonal tile needs element mask)
    const int qrow0 = qb + w * 16 + ((lane >> 4) << 2);
#pragma unroll
    for (int n = 0; n < 4; ++n) {
      int kvcol = kt * 64 + n * 16 + (lane & 15);
#pragma unroll
      for (int r = 0; r < 4; ++r) {
        float sv = sacc[n][r] * 0.125f;
        if (kvcol > qrow0 + r) sv = -1e30f;
        sacc[n][r] = sv;
      }
    }

    // online softmax: row max/sum via 16-lane butterflies
    float mnew[4], alpha[4];
#pragma unroll
    for (int r = 0; r < 4; ++r) {
      float mx = fmaxf(fmaxf(sacc[0][r], sacc[1][r]), fmaxf(sacc[2][r], sacc[3][r]));
#pragma unroll
      for (int d = 1; d < 16; d <<= 1) mx = fmaxf(mx, __shfl_xor(mx, d, 64));
      mnew[r] = fmaxf(mrow[r], mx);
      alpha[r] = __expf(mrow[r] - mnew[r]);
      mrow[r] = mnew[r];
    }
#pragma unroll
    for (int r = 0; r < 4; ++r) {
      float s = 0.f;
#pragma unroll
      for (int n = 0; n < 4; ++n) {
        float p = __expf(sacc[n][r] - mnew[r]);
        sacc[n][r] = p;
        s += p;
      }
#pragma unroll
      for (int d = 1; d < 16; d <<= 1) s += __shfl_xor(s, d, 64);
      lrow[r] = lrow[r] * alpha[r] + s;
    }
#pragma unroll
    for (int n = 0; n < 4; ++n)
#pragma unroll
      for (int r = 0; r < 4; ++r) o[n][r] *= alpha[r];

    // P -> LDS (per-wave region; DS ops in-order within a wave)
#pragma unroll
    for (int n = 0; n < 4; ++n)
#pragma unroll
      for (int r = 0; r < 4; ++r)
        Psm[w][((lane >> 4) << 2) + r][n * 16 + (lane & 15)] = (bf16_t)sacc[n][r];

    // O += P @ V
#pragma unroll
    for (int t = 0; t < 2; ++t) {
      const int kk = t * 32 + ((lane >> 4) << 3);
      bf16x8 pf = *reinterpret_cast<const bf16x8*>(&Psm[w][lane & 15][kk]);
#pragma unroll
      for (int n = 0; n < 4; ++n) {
        bf16x8 vf = *reinterpret_cast<const bf16x8*>(&Vt[n * 16 + (lane & 15)][kk]);
        o[n] = __builtin_amdgcn_mfma_f32_16x16x32_bf16(pf, vf, o[n], 0, 0, 0);
      }
    }
  }

  // epilogue: normalize, write attn output in (B,S,D) layout bf16
  const int qg = qb + w * 16 + ((lane >> 4) << 2);
#pragma unroll
  for (int n = 0; n < 4; ++n)
#pragma unroll
    for (int r = 0; r < 4; ++r) {
      float v = o[n][r] / lrow[r];
      int srow = qg + r;
      AO[((size_t)(b * S_ + srow)) * 1024 + h * 64 + n * 16 + (lane & 15)] = (bf16_t)v;
    }
}

// ---------------- launch -----------------------------------------------------
extern "C" void kernel_launch(void* const* d_in, const int* in_sizes, int n_in,
                              void* d_out, int out_size, void* d_ws, size_t ws_size,
                              hipStream_t stream) {
  const float* x  = (const float*)d_in[0];
  const float* Wq = (const float*)d_in[1];
  const float* Wk = (const float*)d_in[2];
  const float* Wv = (const float*)d_in[3];
  const float* Wo = (const float*)d_in[4];
  const int* tp   = (const int*)d_in[5];

  char* ws = (char*)d_ws;
  bf16_t* xb   = (bf16_t*)(ws);               // 4096x1024      (8 MB)
  bf16_t* Wcat = (bf16_t*)(ws + 8388608);     // 3072x1024      (6 MB)
  bf16_t* Wob  = (bf16_t*)(ws + 14680064);    // 1024x1024      (2 MB)
  bf16_t* QKV  = (bf16_t*)(ws + 16777216);    // 4096x3072      (24 MB)
  bf16_t* Qr   = (bf16_t*)(ws + 41943040);    // (B,H,S,64)     (8 MB)
  bf16_t* Kr   = (bf16_t*)(ws + 50331648);    // (8 MB)
  bf16_t* Vr   = (bf16_t*)(ws + 58720256);    // (8 MB)
  bf16_t* AO   = (bf16_t*)(ws + 67108864);    // 4096x1024      (8 MB)

  cast_bf16_vec<<<dim3(4096), dim3(256), 0, stream>>>(x, xb, 1048576);
  cast_bf16_vec<<<dim3(1024), dim3(256), 0, stream>>>(Wq, Wcat, 262144);
  cast_bf16_vec<<<dim3(1024), dim3(256), 0, stream>>>(Wk, Wcat + 1048576, 262144);
  cast_bf16_vec<<<dim3(1024), dim3(256), 0, stream>>>(Wv, Wcat + 2097152, 262144);
  cast_bf16_vec<<<dim3(1024), dim3(256), 0, stream>>>(Wo, Wob, 262144);

  gemm_bt<false><<<dim3(32, 24), dim3(256), 0, stream>>>(xb, Wcat, (void*)QKV, 3072, 1024);
  rope_reorder<<<dim3(8192), dim3(256), 0, stream>>>(QKV, tp, Qr, Kr, Vr);
  attn_kernel<<<dim3(32, 32), dim3(256), 0, stream>>>(Qr, Kr, Vr, AO);
  gemm_bt<true><<<dim3(32, 8), dim3(256), 0, stream>>>(AO, Wob, d_out, 1024, 1024);

  (void)in_sizes; (void)n_in; (void)out_size; (void)ws_size;
}

// Round 2
// 187.264 us; speedup vs baseline: 1.4151x; 1.4151x over previous
//
#include <hip/hip_runtime.h>
#include <hip/hip_bf16.h>
#include <math.h>

#define B_ 2
#define S_ 2048
#define D_ 1024
#define H_ 16
#define DK_ 64

typedef __bf16 bf16_t;
typedef bf16_t bf16x8 __attribute__((ext_vector_type(8)));
typedef bf16_t bf16x4 __attribute__((ext_vector_type(4)));
typedef float f32x4 __attribute__((ext_vector_type(4)));

// async global->LDS, 16B per lane. LDS dest must be wave-uniform base; HW adds lane*16.
__device__ __forceinline__ void gload16(const void* g, void* lds_base_uniform) {
  __builtin_amdgcn_global_load_lds(
      (const __attribute__((address_space(1))) unsigned int*)g,
      (__attribute__((address_space(3))) unsigned int*)lds_base_uniform, 16, 0, 0);
}

// ---------------- cast fp32 -> bf16, vectorized ----------------
__global__ __launch_bounds__(256) void cast_bf16_vec(const float* __restrict__ in,
                                                     bf16_t* __restrict__ out, int n4) {
  int i = blockIdx.x * 256 + threadIdx.x;
  if (i >= n4) return;
  float4 f = reinterpret_cast<const float4*>(in)[i];
  bf16x4 o;
  o[0] = (bf16_t)f.x; o[1] = (bf16_t)f.y; o[2] = (bf16_t)f.z; o[3] = (bf16_t)f.w;
  reinterpret_cast<bf16x4*>(out)[i] = o;
}

// ---------------- GEMM (m97 structure): C[M,N] = A[M,K] * W[N,K]^T ----------
// 128x128 tile, BK=64, 256 threads (4 waves, 2x2 of 64x64), linear LDS +
// global_load_lds width-16 staging.
template <bool OUT_F32>
__global__ __launch_bounds__(256) void gemm_bt(const bf16_t* __restrict__ A,
                                               const bf16_t* __restrict__ W,
                                               void* __restrict__ Cout,
                                               int Ndim, int Kdim) {
  __shared__ __attribute__((aligned(16))) bf16_t As[128][64];
  __shared__ __attribute__((aligned(16))) bf16_t Bs[128][64];
  const int bm = blockIdx.x * 128;
  const int bn = blockIdx.y * 128;
  const int tid = threadIdx.x;
  const int lane = tid & 63;
  const int w = tid >> 6;
  const int wr = w >> 1, wc = w & 1;
  // staging geometry: tile = 16KB = 16 chunks of 1KB; wave w stages chunks 4w..4w+3
  const int srow_in_chunk = lane >> 3;          // 0..7
  const int scol = (lane & 7) << 3;             // 0..56 step 8 (bf16 elems)

  f32x4 acc[4][4];
  for (int m = 0; m < 4; ++m)
    for (int n = 0; n < 4; ++n) acc[m][n] = (f32x4){0.f, 0.f, 0.f, 0.f};

  for (int k0 = 0; k0 < Kdim; k0 += 64) {
    __syncthreads();
#pragma unroll
    for (int it = 0; it < 4; ++it) {
      const int c = w * 4 + it;               // chunk 0..15
      const int r = c * 8 + srow_in_chunk;    // tile row
      gload16(&A[(size_t)(bm + r) * Kdim + k0 + scol], (char*)&As[0][0] + c * 1024);
      gload16(&W[(size_t)(bn + r) * Kdim + k0 + scol], (char*)&Bs[0][0] + c * 1024);
    }
    __syncthreads();
#pragma unroll
    for (int t = 0; t < 2; ++t) {
      const int kk = t * 32 + ((lane >> 4) << 3);
      bf16x8 af[4], bfr[4];
#pragma unroll
      for (int m = 0; m < 4; ++m)
        af[m] = *reinterpret_cast<const bf16x8*>(&As[wr * 64 + m * 16 + (lane & 15)][kk]);
#pragma unroll
      for (int n = 0; n < 4; ++n)
        bfr[n] = *reinterpret_cast<const bf16x8*>(&Bs[wc * 64 + n * 16 + (lane & 15)][kk]);
#pragma unroll
      for (int m = 0; m < 4; ++m)
#pragma unroll
        for (int n = 0; n < 4; ++n)
          acc[m][n] = __builtin_amdgcn_mfma_f32_16x16x32_bf16(af[m], bfr[n], acc[m][n], 0, 0, 0);
    }
  }

  const int rg = (lane >> 4) << 2, c0 = lane & 15;
#pragma unroll
  for (int m = 0; m < 4; ++m)
#pragma unroll
    for (int n = 0; n < 4; ++n) {
      int r = bm + wr * 64 + m * 16 + rg;
      int c = bn + wc * 64 + n * 16 + c0;
#pragma unroll
      for (int i = 0; i < 4; ++i) {
        if (OUT_F32)
          reinterpret_cast<float*>(Cout)[(size_t)(r + i) * Ndim + c] = acc[m][n][i];
        else
          reinterpret_cast<bf16_t*>(Cout)[(size_t)(r + i) * Ndim + c] = (bf16_t)acc[m][n][i];
      }
    }
}

// ---------------- RoPE (interleaved pairs) + head reorder for Q,K -----------
__global__ __launch_bounds__(256) void rope_qk(const bf16_t* __restrict__ QKV,
                                               const int* __restrict__ posids,
                                               bf16_t* __restrict__ Qr,
                                               bf16_t* __restrict__ Kr) {
  int idx = blockIdx.x * 256 + threadIdx.x;  // (b,s,h,i) i in [0,32)
  int i = idx & 31;
  int h = (idx >> 5) & (H_ - 1);
  int s = (idx >> 9) & (S_ - 1);
  int b = idx >> 20;
  int p = posids[b * S_ + s];
  float ang = (float)p * __expf(-(float)(2 * i) * (9.210340371976184f / 64.0f));
  float cs = cosf(ang), sn = sinf(ang);
  size_t inbase = ((size_t)(b * S_ + s)) * 3072 + h * 64 + 2 * i;
  float q0 = (float)QKV[inbase],        q1 = (float)QKV[inbase + 1];
  float k0 = (float)QKV[inbase + 1024], k1 = (float)QKV[inbase + 1025];
  size_t obase = ((size_t)((b * H_ + h) * S_ + s)) * 64 + 2 * i;
  Qr[obase]     = (bf16_t)(cs * q0 - sn * q1);
  Qr[obase + 1] = (bf16_t)(sn * q0 + cs * q1);
  Kr[obase]     = (bf16_t)(cs * k0 - sn * k1);
  Kr[obase + 1] = (bf16_t)(sn * k0 + cs * k1);
}

// ---------------- V^T materialization: Vt[bh][dk][s] ------------------------
__global__ __launch_bounds__(256) void vtrans(const bf16_t* __restrict__ QKV,
                                              bf16_t* __restrict__ Vt) {
  __shared__ bf16_t Ts[64][72];
  const int s0 = blockIdx.x * 64;
  const int bh = blockIdx.y;
  const int b = bh >> 4, h = bh & 15;
  const int t = threadIdx.x;
  for (int v = t; v < 512; v += 256) {
    int r = v >> 3, c = (v & 7) << 3;
    *reinterpret_cast<bf16x8*>(&Ts[r][c]) = *reinterpret_cast<const bf16x8*>(
        &QKV[(size_t)(b * S_ + s0 + r) * 3072 + 2048 + h * 64 + c]);
  }
  __syncthreads();
  for (int v = t; v < 512; v += 256) {
    int d = v >> 3, j = (v & 7) << 3;
    bf16x8 o;
#pragma unroll
    for (int jj = 0; jj < 8; ++jj) o[jj] = Ts[j + jj][d];
    *reinterpret_cast<bf16x8*>(&Vt[((size_t)bh * 64 + d) * S_ + s0 + j]) = o;
  }
}

// ---------------- causal flash attention ------------------------------------
// grid: (16, B*H). Block handles Q-tiles qt0 and 31-qt0 (balanced: 33 KV tiles).
// 4 waves; wave w owns 16 Q rows of the current 64-row tile.
__global__ __launch_bounds__(256) void attn_kernel(const bf16_t* __restrict__ Qr,
                                                   const bf16_t* __restrict__ Kr,
                                                   const bf16_t* __restrict__ Vt,
                                                   bf16_t* __restrict__ AO) {
  const int bh = blockIdx.y;
  const int b = bh >> 4, h = bh & 15;
  const bf16_t* Qp = Qr + (size_t)bh * S_ * 64;
  const bf16_t* Kp = Kr + (size_t)bh * S_ * 64;
  const bf16_t* Vtp = Vt + (size_t)bh * 64 * S_;
  const int tid = threadIdx.x, lane = tid & 63, w = tid >> 6;

  __shared__ __attribute__((aligned(16))) bf16_t Ksm[64][72];
  __shared__ __attribute__((aligned(16))) bf16_t Vts[64][72];  // [dk][kv]
  __shared__ __attribute__((aligned(16))) bf16_t Psm[4][16][72];

  const int NT = S_ / 64;
#pragma unroll 1
  for (int ph = 0; ph < 2; ++ph) {
    const int qt = ph == 0 ? blockIdx.x : (NT - 1 - blockIdx.x);
    const int qb = qt * 64;

    bf16x8 qf[2];
    {
      int qrow = qb + w * 16 + (lane & 15);
#pragma unroll
      for (int t = 0; t < 2; ++t)
        qf[t] = *reinterpret_cast<const bf16x8*>(
            &Qp[(size_t)qrow * 64 + t * 32 + ((lane >> 4) << 3)]);
    }

    f32x4 o[4];
    for (int n = 0; n < 4; ++n) o[n] = (f32x4){0.f, 0.f, 0.f, 0.f};
    float mrow[4] = {-1e30f, -1e30f, -1e30f, -1e30f};
    float lrow[4] = {0.f, 0.f, 0.f, 0.f};

#pragma unroll 1
    for (int kt = 0; kt <= qt; ++kt) {
      __syncthreads();
      for (int v = tid; v < 512; v += 256) {
        int r = v >> 3, c = (v & 7) << 3;
        *reinterpret_cast<bf16x8*>(&Ksm[r][c]) =
            *reinterpret_cast<const bf16x8*>(&Kp[(size_t)(kt * 64 + r) * 64 + c]);
        *reinterpret_cast<bf16x8*>(&Vts[r][c]) =
            *reinterpret_cast<const bf16x8*>(&Vtp[(size_t)r * S_ + kt * 64 + c]);
      }
      __syncthreads();

      f32x4 sacc[4];
      for (int n = 0; n < 4; ++n) sacc[n] = (f32x4){0.f, 0.f, 0.f, 0.f};
#pragma unroll
      for (int t = 0; t < 2; ++t) {
        const int kk = t * 32 + ((lane >> 4) << 3);
#pragma unroll
        for (int n = 0; n < 4; ++n) {
          bf16x8 kfr = *reinterpret_cast<const bf16x8*>(&Ksm[n * 16 + (lane & 15)][kk]);
          sacc[n] = __builtin_amdgcn_mfma_f32_16x16x32_bf16(qf[t], kfr, sacc[n], 0, 0, 0);
        }
      }

      const int qrow0 = qb + w * 16 + ((lane >> 4) << 2);
      const bool diag = (kt == qt);
#pragma unroll
      for (int n = 0; n < 4; ++n) {
        int kvcol = kt * 64 + n * 16 + (lane & 15);
#pragma unroll
        for (int r = 0; r < 4; ++r) {
          float sv = sacc[n][r] * 0.125f;
          if (diag && kvcol > qrow0 + r) sv = -1e30f;
          sacc[n][r] = sv;
        }
      }

      float mnew[4], alpha[4];
#pragma unroll
      for (int r = 0; r < 4; ++r) {
        float mx = fmaxf(fmaxf(sacc[0][r], sacc[1][r]), fmaxf(sacc[2][r], sacc[3][r]));
#pragma unroll
        for (int d = 1; d < 16; d <<= 1) mx = fmaxf(mx, __shfl_xor(mx, d, 64));
        mnew[r] = fmaxf(mrow[r], mx);
        alpha[r] = __expf(mrow[r] - mnew[r]);
        mrow[r] = mnew[r];
      }
#pragma unroll
      for (int r = 0; r < 4; ++r) {
        float s = 0.f;
#pragma unroll
        for (int n = 0; n < 4; ++n) {
          float p = __expf(sacc[n][r] - mnew[r]);
          sacc[n][r] = p;
          s += p;
        }
#pragma unroll
        for (int d = 1; d < 16; d <<= 1) s += __shfl_xor(s, d, 64);
        lrow[r] = lrow[r] * alpha[r] + s;
      }
#pragma unroll
      for (int n = 0; n < 4; ++n)
#pragma unroll
        for (int r = 0; r < 4; ++r) o[n][r] *= alpha[r];

#pragma unroll
      for (int n = 0; n < 4; ++n)
#pragma unroll
        for (int r = 0; r < 4; ++r)
          Psm[w][((lane >> 4) << 2) + r][n * 16 + (lane & 15)] = (bf16_t)sacc[n][r];

#pragma unroll
      for (int t = 0; t < 2; ++t) {
        const int kk = t * 32 + ((lane >> 4) << 3);
        bf16x8 pf = *reinterpret_cast<const bf16x8*>(&Psm[w][lane & 15][kk]);
#pragma unroll
        for (int n = 0; n < 4; ++n) {
          bf16x8 vf = *reinterpret_cast<const bf16x8*>(&Vts[n * 16 + (lane & 15)][kk]);
          o[n] = __builtin_amdgcn_mfma_f32_16x16x32_bf16(pf, vf, o[n], 0, 0, 0);
        }
      }
    }

    const int qg = qb + w * 16 + ((lane >> 4) << 2);
#pragma unroll
    for (int n = 0; n < 4; ++n)
#pragma unroll
      for (int r = 0; r < 4; ++r) {
        float v = o[n][r] / lrow[r];
        int srow = qg + r;
        AO[((size_t)(b * S_ + srow)) * 1024 + h * 64 + n * 16 + (lane & 15)] = (bf16_t)v;
      }
  }
}

// ---------------- launch -----------------------------------------------------
extern "C" void kernel_launch(void* const* d_in, const int* in_sizes, int n_in,
                              void* d_out, int out_size, void* d_ws, size_t ws_size,
                              hipStream_t stream) {
  const float* x  = (const float*)d_in[0];
  const float* Wq = (const float*)d_in[1];
  const float* Wk = (const float*)d_in[2];
  const float* Wv = (const float*)d_in[3];
  const float* Wo = (const float*)d_in[4];
  const int* tp   = (const int*)d_in[5];

  char* ws = (char*)d_ws;
  bf16_t* xb   = (bf16_t*)(ws);               // 4096x1024      (8 MB)
  bf16_t* Wcat = (bf16_t*)(ws + 8388608);     // 3072x1024      (6 MB)
  bf16_t* Wob  = (bf16_t*)(ws + 14680064);    // 1024x1024      (2 MB)
  bf16_t* QKV  = (bf16_t*)(ws + 16777216);    // 4096x3072      (24 MB)
  bf16_t* Qr   = (bf16_t*)(ws + 41943040);    // (B,H,S,64)     (8 MB)
  bf16_t* Kr   = (bf16_t*)(ws + 50331648);    // (8 MB)
  bf16_t* Vt   = (bf16_t*)(ws + 58720256);    // (B,H,64,S)     (8 MB)
  bf16_t* AO   = (bf16_t*)(ws + 67108864);    // 4096x1024      (8 MB)

  cast_bf16_vec<<<dim3(4096), dim3(256), 0, stream>>>(x, xb, 1048576);
  cast_bf16_vec<<<dim3(1024), dim3(256), 0, stream>>>(Wq, Wcat, 262144);
  cast_bf16_vec<<<dim3(1024), dim3(256), 0, stream>>>(Wk, Wcat + 1048576, 262144);
  cast_bf16_vec<<<dim3(1024), dim3(256), 0, stream>>>(Wv, Wcat + 2097152, 262144);
  cast_bf16_vec<<<dim3(1024), dim3(256), 0, stream>>>(Wo, Wob, 262144);

  gemm_bt<false><<<dim3(32, 24), dim3(256), 0, stream>>>(xb, Wcat, (void*)QKV, 3072, 1024);
  rope_qk<<<dim3(8192), dim3(256), 0, stream>>>(QKV, tp, Qr, Kr);
  vtrans<<<dim3(32, 32), dim3(256), 0, stream>>>(QKV, Vt);
  attn_kernel<<<dim3(16, 32), dim3(256), 0, stream>>>(Qr, Kr, Vt, AO);
  gemm_bt<true><<<dim3(32, 8), dim3(256), 0, stream>>>(AO, Wob, d_out, 1024, 1024);

  (void)in_sizes; (void)n_in; (void)out_size; (void)ws_size;
}

// Round 5
// 177.539 us; speedup vs baseline: 1.4926x; 1.0548x over previous
//
#include <hip/hip_runtime.h>
#include <hip/hip_bf16.h>
#include <math.h>

#define B_ 2
#define S_ 2048
#define D_ 1024
#define H_ 16
#define DK_ 64

typedef __bf16 bf16_t;
typedef bf16_t bf16x8 __attribute__((ext_vector_type(8)));
typedef bf16_t bf16x4 __attribute__((ext_vector_type(4)));
typedef float f32x4 __attribute__((ext_vector_type(4)));

// async global->LDS, 16B per lane. LDS dest base must be wave-uniform; HW adds lane*16.
__device__ __forceinline__ void gload16(const void* g, void* lds_base_uniform) {
  __builtin_amdgcn_global_load_lds(
      (const __attribute__((address_space(1))) unsigned int*)g,
      (__attribute__((address_space(3))) unsigned int*)lds_base_uniform, 16, 0, 0);
}

// ---------------- cast fp32 -> bf16, vectorized ----------------
__global__ __launch_bounds__(256) void cast_bf16_vec(const float* __restrict__ in,
                                                     bf16_t* __restrict__ out, int n4) {
  int i = blockIdx.x * 256 + threadIdx.x;
  if (i >= n4) return;
  float4 f = reinterpret_cast<const float4*>(in)[i];
  bf16x4 o;
  o[0] = (bf16_t)f.x; o[1] = (bf16_t)f.y; o[2] = (bf16_t)f.z; o[3] = (bf16_t)f.w;
  reinterpret_cast<bf16x4*>(out)[i] = o;
}

// ---------------- GEMM (m97 structure): C[M,N] = A[M,K] * W[N,K]^T ----------
template <bool OUT_F32>
__global__ __launch_bounds__(256) void gemm_bt(const bf16_t* __restrict__ A,
                                               const bf16_t* __restrict__ W,
                                               void* __restrict__ Cout,
                                               int Ndim, int Kdim) {
  __shared__ __attribute__((aligned(16))) bf16_t As[128][64];
  __shared__ __attribute__((aligned(16))) bf16_t Bs[128][64];
  const int bm = blockIdx.x * 128;
  const int bn = blockIdx.y * 128;
  const int tid = threadIdx.x;
  const int lane = tid & 63;
  const int w = tid >> 6;
  const int wr = w >> 1, wc = w & 1;
  const int srow_in_chunk = lane >> 3;
  const int scol = (lane & 7) << 3;

  f32x4 acc[4][4];
  for (int m = 0; m < 4; ++m)
    for (int n = 0; n < 4; ++n) acc[m][n] = (f32x4){0.f, 0.f, 0.f, 0.f};

  for (int k0 = 0; k0 < Kdim; k0 += 64) {
    __syncthreads();
#pragma unroll
    for (int it = 0; it < 4; ++it) {
      const int c = w * 4 + it;
      const int r = c * 8 + srow_in_chunk;
      gload16(&A[(size_t)(bm + r) * Kdim + k0 + scol], (char*)&As[0][0] + c * 1024);
      gload16(&W[(size_t)(bn + r) * Kdim + k0 + scol], (char*)&Bs[0][0] + c * 1024);
    }
    __syncthreads();
#pragma unroll
    for (int t = 0; t < 2; ++t) {
      const int kk = t * 32 + ((lane >> 4) << 3);
      bf16x8 af[4], bfr[4];
#pragma unroll
      for (int m = 0; m < 4; ++m)
        af[m] = *reinterpret_cast<const bf16x8*>(&As[wr * 64 + m * 16 + (lane & 15)][kk]);
#pragma unroll
      for (int n = 0; n < 4; ++n)
        bfr[n] = *reinterpret_cast<const bf16x8*>(&Bs[wc * 64 + n * 16 + (lane & 15)][kk]);
#pragma unroll
      for (int m = 0; m < 4; ++m)
#pragma unroll
        for (int n = 0; n < 4; ++n)
          acc[m][n] = __builtin_amdgcn_mfma_f32_16x16x32_bf16(af[m], bfr[n], acc[m][n], 0, 0, 0);
    }
  }

  const int rg = (lane >> 4) << 2, c0 = lane & 15;
#pragma unroll
  for (int m = 0; m < 4; ++m)
#pragma unroll
    for (int n = 0; n < 4; ++n) {
      int r = bm + wr * 64 + m * 16 + rg;
      int c = bn + wc * 64 + n * 16 + c0;
#pragma unroll
      for (int i = 0; i < 4; ++i) {
        if (OUT_F32)
          reinterpret_cast<float*>(Cout)[(size_t)(r + i) * Ndim + c] = acc[m][n][i];
        else
          reinterpret_cast<bf16_t*>(Cout)[(size_t)(r + i) * Ndim + c] = (bf16_t)acc[m][n][i];
      }
    }
}

// ---------------- RoPE (interleaved pairs) + head reorder for Q,K -----------
// Q is pre-scaled by 1/sqrt(dk)=0.125 (exact in bf16).
__global__ __launch_bounds__(256) void rope_qk(const bf16_t* __restrict__ QKV,
                                               const int* __restrict__ posids,
                                               bf16_t* __restrict__ Qr,
                                               bf16_t* __restrict__ Kr) {
  int idx = blockIdx.x * 256 + threadIdx.x;  // (b,s,h,i) i in [0,32)
  int i = idx & 31;
  int h = (idx >> 5) & (H_ - 1);
  int s = (idx >> 9) & (S_ - 1);
  int b = idx >> 20;
  int p = posids[b * S_ + s];
  float ang = (float)p * __expf(-(float)(2 * i) * (9.210340371976184f / 64.0f));
  float cs = cosf(ang), sn = sinf(ang);
  size_t inbase = ((size_t)(b * S_ + s)) * 3072 + h * 64 + 2 * i;
  float q0 = (float)QKV[inbase],        q1 = (float)QKV[inbase + 1];
  float k0 = (float)QKV[inbase + 1024], k1 = (float)QKV[inbase + 1025];
  size_t obase = ((size_t)((b * H_ + h) * S_ + s)) * 64 + 2 * i;
  Qr[obase]     = (bf16_t)((cs * q0 - sn * q1) * 0.125f);
  Qr[obase + 1] = (bf16_t)((sn * q0 + cs * q1) * 0.125f);
  Kr[obase]     = (bf16_t)(cs * k0 - sn * k1);
  Kr[obase + 1] = (bf16_t)(sn * k0 + cs * k1);
}

// ---------------- V^T materialization: Vt[bh][dk][s] ------------------------
__global__ __launch_bounds__(256) void vtrans(const bf16_t* __restrict__ QKV,
                                              bf16_t* __restrict__ Vt) {
  __shared__ bf16_t Ts[64][72];
  const int s0 = blockIdx.x * 64;
  const int bh = blockIdx.y;
  const int b = bh >> 4, h = bh & 15;
  const int t = threadIdx.x;
  for (int v = t; v < 512; v += 256) {
    int r = v >> 3, c = (v & 7) << 3;
    *reinterpret_cast<bf16x8*>(&Ts[r][c]) = *reinterpret_cast<const bf16x8*>(
        &QKV[(size_t)(b * S_ + s0 + r) * 3072 + 2048 + h * 64 + c]);
  }
  __syncthreads();
  for (int v = t; v < 512; v += 256) {
    int d = v >> 3, j = (v & 7) << 3;
    bf16x8 o;
#pragma unroll
    for (int jj = 0; jj < 8; ++jj) o[jj] = Ts[j + jj][d];
    *reinterpret_cast<bf16x8*>(&Vt[((size_t)bh * 64 + d) * S_ + s0 + j]) = o;
  }
}

// ---------------- causal flash attention ------------------------------------
// grid: 512 linear blocks, 512 threads (8 waves). Block = (bh, 128-row Q
// supertile): bh = linear & 31, qt = linear >> 5, reversed for odd bh so
// heavy/light supertiles interleave in dispatch order.
// KV tiles of 64 staged via double-buffered global_load_lds with XOR swizzle.
__global__ __launch_bounds__(512) void attn_kernel(const bf16_t* __restrict__ Qr,
                                                   const bf16_t* __restrict__ Kr,
                                                   const bf16_t* __restrict__ Vt,
                                                   bf16_t* __restrict__ AO) {
  const int linear = blockIdx.x;
  const int bh = linear & 31;
  int qt = linear >> 5;
  if (bh & 1) qt = 15 - qt;
  const int b = bh >> 4, h = bh & 15;
  const bf16_t* Qp = Qr + (size_t)bh * S_ * 64;
  const char* Kbase = (const char*)(Kr + (size_t)bh * S_ * 64);
  const char* Vbase = (const char*)(Vt + (size_t)bh * 64 * S_);
  const int tid = threadIdx.x, lane = tid & 63, w = tid >> 6;
  const int qb = qt * 128;
  const int nt = 2 * qt + 2;

  __shared__ __attribute__((aligned(16))) bf16_t Ksm[2][64][64];
  __shared__ __attribute__((aligned(16))) bf16_t Vts[2][64][64];
  __shared__ __attribute__((aligned(16))) bf16_t Psm[8][16][72];

  // staging: wave w stages 1KB chunk w of each 8KB tile. Global source slot is
  // pre-swizzled (slot ^= row&7) so swizzled reads see correct data (rule #21).
  const int srow = lane >> 3;       // row within chunk, 0..7
  const int sslot = lane & 7;       // 16B slot within row

  // Q fragments, wave w owns rows qb + w*16 .. +15 (Q pre-scaled by 0.125)
  bf16x8 qf[2];
  {
    int qrow = qb + w * 16 + (lane & 15);
#pragma unroll
    for (int t = 0; t < 2; ++t)
      qf[t] = *reinterpret_cast<const bf16x8*>(
          &Qp[(size_t)qrow * 64 + t * 32 + ((lane >> 4) << 3)]);
  }

  f32x4 o[4];
  for (int n = 0; n < 4; ++n) o[n] = (f32x4){0.f, 0.f, 0.f, 0.f};
  float mrow[4] = {-1e30f, -1e30f, -1e30f, -1e30f};
  float lrow[4] = {0.f, 0.f, 0.f, 0.f};

  // prologue: stage tile 0 into buf 0
  {
    int row = 8 * w + srow;
    gload16(Kbase + (size_t)row * 128 + ((sslot ^ (row & 7)) << 4),
            (char*)&Ksm[0][0][0] + w * 1024);
    gload16(Vbase + (size_t)row * (S_ * 2) + ((sslot ^ (row & 7)) << 4),
            (char*)&Vts[0][0][0] + w * 1024);
  }
  __syncthreads();

  int cur = 0;
#pragma unroll 1
  for (int kt = 0; kt < nt; ++kt) {
    // issue next tile's loads (overlap with compute below)
    if (kt + 1 < nt) {
      int row = 8 * w + srow;
      gload16(Kbase + (size_t)(kt + 1) * 8192 + (size_t)row * 128 + ((sslot ^ (row & 7)) << 4),
              (char*)&Ksm[cur ^ 1][0][0] + w * 1024);
      gload16(Vbase + (size_t)row * (S_ * 2) + (size_t)(kt + 1) * 128 + ((sslot ^ (row & 7)) << 4),
              (char*)&Vts[cur ^ 1][0][0] + w * 1024);
    }

    // ---- S = Q K^T (wave strip 16 x 64), swizzled reads ----
    f32x4 sacc[4];
    for (int n = 0; n < 4; ++n) sacc[n] = (f32x4){0.f, 0.f, 0.f, 0.f};
#pragma unroll
    for (int t = 0; t < 2; ++t) {
      const int slot0 = t * 4 + (lane >> 4);   // 16B slot index of kk
#pragma unroll
      for (int n = 0; n < 4; ++n) {
        const int R = n * 16 + (lane & 15);
        bf16x8 kfr = *reinterpret_cast<const bf16x8*>(
            (const char*)&Ksm[cur][0][0] + R * 128 + ((slot0 ^ (R & 7)) << 4));
        sacc[n] = __builtin_amdgcn_mfma_f32_16x16x32_bf16(qf[t], kfr, sacc[n], 0, 0, 0);
      }
    }

    // ---- causal mask: needed when max kvcol of tile exceeds wave's min row ----
    const int wr0 = qb + w * 16;
    const int qrow0 = wr0 + ((lane >> 4) << 2);
    if (kt * 64 + 63 > wr0) {
#pragma unroll
      for (int n = 0; n < 4; ++n) {
        int kvcol = kt * 64 + n * 16 + (lane & 15);
#pragma unroll
        for (int r = 0; r < 4; ++r)
          if (kvcol > qrow0 + r) sacc[n][r] = -1e30f;
      }
    }

    // ---- online softmax ----
    float mnew[4], alpha[4];
#pragma unroll
    for (int r = 0; r < 4; ++r) {
      float mx = fmaxf(fmaxf(sacc[0][r], sacc[1][r]), fmaxf(sacc[2][r], sacc[3][r]));
#pragma unroll
      for (int d = 1; d < 16; d <<= 1) mx = fmaxf(mx, __shfl_xor(mx, d, 64));
      mnew[r] = fmaxf(mrow[r], mx);
      alpha[r] = __expf(mrow[r] - mnew[r]);
      mrow[r] = mnew[r];
    }
#pragma unroll
    for (int r = 0; r < 4; ++r) {
      float s = 0.f;
#pragma unroll
      for (int n = 0; n < 4; ++n) {
        float p = __expf(sacc[n][r] - mnew[r]);
        sacc[n][r] = p;
        s += p;
      }
#pragma unroll
      for (int d = 1; d < 16; d <<= 1) s += __shfl_xor(s, d, 64);
      lrow[r] = lrow[r] * alpha[r] + s;
    }
#pragma unroll
    for (int n = 0; n < 4; ++n)
#pragma unroll
      for (int r = 0; r < 4; ++r) o[n][r] *= alpha[r];

    // ---- P -> per-wave LDS (in-wave DS ordering, no barrier needed) ----
#pragma unroll
    for (int n = 0; n < 4; ++n)
#pragma unroll
      for (int r = 0; r < 4; ++r)
        Psm[w][((lane >> 4) << 2) + r][n * 16 + (lane & 15)] = (bf16_t)sacc[n][r];

    // ---- O += P @ V (V^T tile, swizzled reads) ----
#pragma unroll
    for (int t = 0; t < 2; ++t) {
      const int kk = t * 32 + ((lane >> 4) << 3);
      const int slot0 = t * 4 + (lane >> 4);
      bf16x8 pf = *reinterpret_cast<const bf16x8*>(&Psm[w][lane & 15][kk]);
#pragma unroll
      for (int n = 0; n < 4; ++n) {
        const int R = n * 16 + (lane & 15);
        bf16x8 vf = *reinterpret_cast<const bf16x8*>(
            (const char*)&Vts[cur][0][0] + R * 128 + ((slot0 ^ (R & 7)) << 4));
        o[n] = __builtin_amdgcn_mfma_f32_16x16x32_bf16(pf, vf, o[n], 0, 0, 0);
      }
    }

    __syncthreads();   // drains this iteration's prefetch; syncs buffer swap
    cur ^= 1;
  }

  // ---- epilogue ----
  const int qg = qb + w * 16 + ((lane >> 4) << 2);
#pragma unroll
  for (int n = 0; n < 4; ++n)
#pragma unroll
    for (int r = 0; r < 4; ++r) {
      float v = o[n][r] / lrow[r];
      int srow_ = qg + r;
      AO[((size_t)(b * S_ + srow_)) * 1024 + h * 64 + n * 16 + (lane & 15)] = (bf16_t)v;
    }
}

// ---------------- launch -----------------------------------------------------
extern "C" void kernel_launch(void* const* d_in, const int* in_sizes, int n_in,
                              void* d_out, int out_size, void* d_ws, size_t ws_size,
                              hipStream_t stream) {
  const float* x  = (const float*)d_in[0];
  const float* Wq = (const float*)d_in[1];
  const float* Wk = (const float*)d_in[2];
  const float* Wv = (const float*)d_in[3];
  const float* Wo = (const float*)d_in[4];
  const int* tp   = (const int*)d_in[5];

  char* ws = (char*)d_ws;
  bf16_t* xb   = (bf16_t*)(ws);               // 4096x1024      (8 MB)
  bf16_t* Wcat = (bf16_t*)(ws + 8388608);     // 3072x1024      (6 MB)
  bf16_t* Wob  = (bf16_t*)(ws + 14680064);    // 1024x1024      (2 MB)
  bf16_t* QKV  = (bf16_t*)(ws + 16777216);    // 4096x3072      (24 MB)
  bf16_t* Qr   = (bf16_t*)(ws + 41943040);    // (B,H,S,64)     (8 MB)
  bf16_t* Kr   = (bf16_t*)(ws + 50331648);    // (8 MB)
  bf16_t* Vt   = (bf16_t*)(ws + 58720256);    // (B,H,64,S)     (8 MB)
  bf16_t* AO   = (bf16_t*)(ws + 67108864);    // 4096x1024      (8 MB)

  cast_bf16_vec<<<dim3(4096), dim3(256), 0, stream>>>(x, xb, 1048576);
  cast_bf16_vec<<<dim3(1024), dim3(256), 0, stream>>>(Wq, Wcat, 262144);
  cast_bf16_vec<<<dim3(1024), dim3(256), 0, stream>>>(Wk, Wcat + 1048576, 262144);
  cast_bf16_vec<<<dim3(1024), dim3(256), 0, stream>>>(Wv, Wcat + 2097152, 262144);
  cast_bf16_vec<<<dim3(1024), dim3(256), 0, stream>>>(Wo, Wob, 262144);

  gemm_bt<false><<<dim3(32, 24), dim3(256), 0, stream>>>(xb, Wcat, (void*)QKV, 3072, 1024);
  rope_qk<<<dim3(8192), dim3(256), 0, stream>>>(QKV, tp, Qr, Kr);
  vtrans<<<dim3(32, 32), dim3(256), 0, stream>>>(QKV, Vt);
  attn_kernel<<<dim3(512), dim3(512), 0, stream>>>(Qr, Kr, Vt, AO);
  gemm_bt<true><<<dim3(32, 8), dim3(256), 0, stream>>>(AO, Wob, d_out, 1024, 1024);

  (void)in_sizes; (void)n_in; (void)out_size; (void)ws_size;
}

// Round 7
// 146.079 us; speedup vs baseline: 1.8141x; 1.2154x over previous
//
#include <hip/hip_runtime.h>
#include <hip/hip_bf16.h>
#include <math.h>

#define B_ 2
#define S_ 2048
#define D_ 1024
#define H_ 16
#define DK_ 64

typedef __bf16 bf16_t;
typedef bf16_t bf16x8 __attribute__((ext_vector_type(8)));
typedef bf16_t bf16x4 __attribute__((ext_vector_type(4)));
typedef float f32x4 __attribute__((ext_vector_type(4)));

// async global->LDS, 16B per lane. LDS dest base must be wave-uniform; HW adds lane*16.
__device__ __forceinline__ void gload16(const void* g, void* lds_base_uniform) {
  __builtin_amdgcn_global_load_lds(
      (const __attribute__((address_space(1))) unsigned int*)g,
      (__attribute__((address_space(3))) unsigned int*)lds_base_uniform, 16, 0, 0);
}

// ---------------- cast fp32 -> bf16, vectorized ----------------
__global__ __launch_bounds__(256) void cast_bf16_vec(const float* __restrict__ in,
                                                     bf16_t* __restrict__ out, int n4) {
  int i = blockIdx.x * 256 + threadIdx.x;
  if (i >= n4) return;
  float4 f = reinterpret_cast<const float4*>(in)[i];
  bf16x4 o;
  o[0] = (bf16_t)f.x; o[1] = (bf16_t)f.y; o[2] = (bf16_t)f.z; o[3] = (bf16_t)f.w;
  reinterpret_cast<bf16x4*>(out)[i] = o;
}

// ---------------- GEMM (m97 structure): C[M,N] = A[M,K] * W[N,K]^T ----------
template <bool OUT_F32>
__global__ __launch_bounds__(256) void gemm_bt(const bf16_t* __restrict__ A,
                                               const bf16_t* __restrict__ W,
                                               void* __restrict__ Cout,
                                               int Ndim, int Kdim) {
  __shared__ __attribute__((aligned(16))) bf16_t As[128][64];
  __shared__ __attribute__((aligned(16))) bf16_t Bs[128][64];
  const int bm = blockIdx.x * 128;
  const int bn = blockIdx.y * 128;
  const int tid = threadIdx.x;
  const int lane = tid & 63;
  const int w = tid >> 6;
  const int wr = w >> 1, wc = w & 1;
  const int srow_in_chunk = lane >> 3;
  const int scol = (lane & 7) << 3;

  f32x4 acc[4][4];
  for (int m = 0; m < 4; ++m)
    for (int n = 0; n < 4; ++n) acc[m][n] = (f32x4){0.f, 0.f, 0.f, 0.f};

  for (int k0 = 0; k0 < Kdim; k0 += 64) {
    __syncthreads();
#pragma unroll
    for (int it = 0; it < 4; ++it) {
      const int c = w * 4 + it;
      const int r = c * 8 + srow_in_chunk;
      gload16(&A[(size_t)(bm + r) * Kdim + k0 + scol], (char*)&As[0][0] + c * 1024);
      gload16(&W[(size_t)(bn + r) * Kdim + k0 + scol], (char*)&Bs[0][0] + c * 1024);
    }
    __syncthreads();
#pragma unroll
    for (int t = 0; t < 2; ++t) {
      const int kk = t * 32 + ((lane >> 4) << 3);
      bf16x8 af[4], bfr[4];
#pragma unroll
      for (int m = 0; m < 4; ++m)
        af[m] = *reinterpret_cast<const bf16x8*>(&As[wr * 64 + m * 16 + (lane & 15)][kk]);
#pragma unroll
      for (int n = 0; n < 4; ++n)
        bfr[n] = *reinterpret_cast<const bf16x8*>(&Bs[wc * 64 + n * 16 + (lane & 15)][kk]);
#pragma unroll
      for (int m = 0; m < 4; ++m)
#pragma unroll
        for (int n = 0; n < 4; ++n)
          acc[m][n] = __builtin_amdgcn_mfma_f32_16x16x32_bf16(af[m], bfr[n], acc[m][n], 0, 0, 0);
    }
  }

  const int rg = (lane >> 4) << 2, c0 = lane & 15;
#pragma unroll
  for (int m = 0; m < 4; ++m)
#pragma unroll
    for (int n = 0; n < 4; ++n) {
      int r = bm + wr * 64 + m * 16 + rg;
      int c = bn + wc * 64 + n * 16 + c0;
#pragma unroll
      for (int i = 0; i < 4; ++i) {
        if (OUT_F32)
          reinterpret_cast<float*>(Cout)[(size_t)(r + i) * Ndim + c] = acc[m][n][i];
        else
          reinterpret_cast<bf16_t*>(Cout)[(size_t)(r + i) * Ndim + c] = (bf16_t)acc[m][n][i];
      }
    }
}

// ---------------- RoPE (interleaved pairs) + head reorder for Q,K -----------
// Q is pre-scaled by 1/sqrt(dk)=0.125 (exact in bf16).
__global__ __launch_bounds__(256) void rope_qk(const bf16_t* __restrict__ QKV,
                                               const int* __restrict__ posids,
                                               bf16_t* __restrict__ Qr,
                                               bf16_t* __restrict__ Kr) {
  int idx = blockIdx.x * 256 + threadIdx.x;  // (b,s,h,i) i in [0,32)
  int i = idx & 31;
  int h = (idx >> 5) & (H_ - 1);
  int s = (idx >> 9) & (S_ - 1);
  int b = idx >> 20;
  int p = posids[b * S_ + s];
  float ang = (float)p * __expf(-(float)(2 * i) * (9.210340371976184f / 64.0f));
  float cs = cosf(ang), sn = sinf(ang);
  size_t inbase = ((size_t)(b * S_ + s)) * 3072 + h * 64 + 2 * i;
  float q0 = (float)QKV[inbase],        q1 = (float)QKV[inbase + 1];
  float k0 = (float)QKV[inbase + 1024], k1 = (float)QKV[inbase + 1025];
  size_t obase = ((size_t)((b * H_ + h) * S_ + s)) * 64 + 2 * i;
  Qr[obase]     = (bf16_t)((cs * q0 - sn * q1) * 0.125f);
  Qr[obase + 1] = (bf16_t)((sn * q0 + cs * q1) * 0.125f);
  Kr[obase]     = (bf16_t)(cs * k0 - sn * k1);
  Kr[obase + 1] = (bf16_t)(sn * k0 + cs * k1);
}

// ---------------- V^T materialization: Vt[bh][dk][s] ------------------------
__global__ __launch_bounds__(256) void vtrans(const bf16_t* __restrict__ QKV,
                                              bf16_t* __restrict__ Vt) {
  __shared__ bf16_t Ts[64][72];
  const int s0 = blockIdx.x * 64;
  const int bh = blockIdx.y;
  const int b = bh >> 4, h = bh & 15;
  const int t = threadIdx.x;
  for (int v = t; v < 512; v += 256) {
    int r = v >> 3, c = (v & 7) << 3;
    *reinterpret_cast<bf16x8*>(&Ts[r][c]) = *reinterpret_cast<const bf16x8*>(
        &QKV[(size_t)(b * S_ + s0 + r) * 3072 + 2048 + h * 64 + c]);
  }
  __syncthreads();
  for (int v = t; v < 512; v += 256) {
    int d = v >> 3, j = (v & 7) << 3;
    bf16x8 o;
#pragma unroll
    for (int jj = 0; jj < 8; ++jj) o[jj] = Ts[j + jj][d];
    *reinterpret_cast<bf16x8*>(&Vt[((size_t)bh * 64 + d) * S_ + s0 + j]) = o;
  }
}

// ---------------- causal flash attention (swapped-operand, per-lane q-row) ---
// grid: 1024 blocks, 256 threads (4 waves). Block = (bh = linear&31,
// qt = 31 - (linear>>5)) : LPT order, heavy supertiles dispatch first.
// Wave w owns q-rows [qt*64 + 16w, +16); lane owns q = lane&15.
// S^T = mfma(K,Q): sacc[m][r] = S[q=lane&15][kcol = kt*64+m*16+(lane>>4)*4+r].
// O^T = mfma(V^T,P): o[m][r] = O[q=lane&15][d = m*16+(lane>>4)*4+r].
__global__ __launch_bounds__(256) void attn_kernel(const bf16_t* __restrict__ Qr,
                                                   const bf16_t* __restrict__ Kr,
                                                   const bf16_t* __restrict__ Vt,
                                                   bf16_t* __restrict__ AO) {
  const int linear = blockIdx.x;
  const int bh = linear & 31;
  const int qt = 31 - (linear >> 5);
  const int b = bh >> 4, h = bh & 15;
  const bf16_t* Qp = Qr + (size_t)bh * S_ * 64;
  const char* Kbase = (const char*)(Kr + (size_t)bh * S_ * 64);
  const char* Vbase = (const char*)(Vt + (size_t)bh * 64 * S_);
  const int tid = threadIdx.x, lane = tid & 63, w = tid >> 6;
  const int qb = qt * 64;
  const int nt = qt + 1;

  __shared__ __attribute__((aligned(16))) bf16_t Ksm[2][64][64];
  __shared__ __attribute__((aligned(16))) bf16_t Vts[2][64][64];
  __shared__ __attribute__((aligned(16))) bf16_t Psm[4][16][72];

  // staging: 8KB tile = 8 chunks of 1KB; wave w stages chunks 2w, 2w+1.
  // Global source slot pre-swizzled (slot ^= row&7); reads XOR the same way.
  const int srow = lane >> 3;
  const int sslot = lane & 7;

  // Q fragments (B-operand): lane provides Q[q=lane&15][k=(lane>>4)*8+e+32t]
  bf16x8 qf[2];
  {
    int qrow = qb + w * 16 + (lane & 15);
#pragma unroll
    for (int t = 0; t < 2; ++t)
      qf[t] = *reinterpret_cast<const bf16x8*>(
          &Qp[(size_t)qrow * 64 + t * 32 + ((lane >> 4) << 3)]);
  }

  f32x4 o[4];
  for (int m = 0; m < 4; ++m) o[m] = (f32x4){0.f, 0.f, 0.f, 0.f};
  float mrow = -1e30f, lrow = 0.f;

  // prologue: stage tile 0 into buf 0
#pragma unroll
  for (int it = 0; it < 2; ++it) {
    int c = 2 * w + it;
    int row = c * 8 + srow;
    gload16(Kbase + (size_t)row * 128 + ((sslot ^ (row & 7)) << 4),
            (char*)&Ksm[0][0][0] + c * 1024);
    gload16(Vbase + (size_t)row * (S_ * 2) + ((sslot ^ (row & 7)) << 4),
            (char*)&Vts[0][0][0] + c * 1024);
  }
  __syncthreads();

  int cur = 0;
#pragma unroll 1
  for (int kt = 0; kt < nt; ++kt) {
    // prefetch next tile (overlaps with compute; drained by end-of-iter barrier)
    if (kt + 1 < nt) {
#pragma unroll
      for (int it = 0; it < 2; ++it) {
        int c = 2 * w + it;
        int row = c * 8 + srow;
        gload16(Kbase + (size_t)(kt + 1) * 8192 + (size_t)row * 128 + ((sslot ^ (row & 7)) << 4),
                (char*)&Ksm[cur ^ 1][0][0] + c * 1024);
        gload16(Vbase + (size_t)row * (S_ * 2) + (size_t)(kt + 1) * 128 + ((sslot ^ (row & 7)) << 4),
                (char*)&Vts[cur ^ 1][0][0] + c * 1024);
      }
    }

    // ---- S^T = K Q^T : swapped operands ----
    f32x4 sacc[4];
    for (int m = 0; m < 4; ++m) sacc[m] = (f32x4){0.f, 0.f, 0.f, 0.f};
#pragma unroll
    for (int t = 0; t < 2; ++t) {
      const int slot0 = t * 4 + (lane >> 4);
#pragma unroll
      for (int m = 0; m < 4; ++m) {
        const int R = m * 16 + (lane & 15);
        bf16x8 kfr = *reinterpret_cast<const bf16x8*>(
            (const char*)&Ksm[cur][0][0] + R * 128 + ((slot0 ^ (R & 7)) << 4));
        sacc[m] = __builtin_amdgcn_mfma_f32_16x16x32_bf16(kfr, qf[t], sacc[m], 0, 0, 0);
      }
    }

    // ---- causal mask (lane's q-row vs per-reg kcol) ----
    const int qrow = qb + w * 16 + (lane & 15);
    const int g4 = (lane >> 4) << 2;
    if (kt * 64 + 63 > qb + w * 16) {
#pragma unroll
      for (int m = 0; m < 4; ++m) {
        const int kc0 = kt * 64 + m * 16 + g4;
#pragma unroll
        for (int r = 0; r < 4; ++r)
          if (kc0 + r > qrow) sacc[m][r] = -1e30f;
      }
    }

    // ---- online softmax: in-lane over 16 + 2 shfl rounds ----
    float mx = sacc[0][0];
#pragma unroll
    for (int m = 0; m < 4; ++m)
#pragma unroll
      for (int r = 0; r < 4; ++r) mx = fmaxf(mx, sacc[m][r]);
    mx = fmaxf(mx, __shfl_xor(mx, 16, 64));
    mx = fmaxf(mx, __shfl_xor(mx, 32, 64));
    const float mnew = fmaxf(mrow, mx);
    const float alpha = __expf(mrow - mnew);
    mrow = mnew;

    float s = 0.f;
#pragma unroll
    for (int m = 0; m < 4; ++m)
#pragma unroll
      for (int r = 0; r < 4; ++r) {
        float p = __expf(sacc[m][r] - mnew);
        sacc[m][r] = p;
        s += p;
      }
    s += __shfl_xor(s, 16, 64);
    s += __shfl_xor(s, 32, 64);
    lrow = lrow * alpha + s;

#pragma unroll
    for (int m = 0; m < 4; ++m)
#pragma unroll
      for (int r = 0; r < 4; ++r) o[m][r] *= alpha;

    // ---- P -> Psm: 4x packed 8B writes (lane's 4 consecutive k per m) ----
    {
      const int q = lane & 15;
#pragma unroll
      for (int m = 0; m < 4; ++m) {
        bf16x4 pk;
#pragma unroll
        for (int r = 0; r < 4; ++r) pk[r] = (bf16_t)sacc[m][r];
        *reinterpret_cast<bf16x4*>(&Psm[w][q][m * 16 + g4]) = pk;
      }
    }

    // ---- O^T += V^T P^T : swapped operands ----
#pragma unroll
    for (int t = 0; t < 2; ++t) {
      const int kk = t * 32 + ((lane >> 4) << 3);
      const int slot0 = t * 4 + (lane >> 4);
      bf16x8 pf = *reinterpret_cast<const bf16x8*>(&Psm[w][lane & 15][kk]);
#pragma unroll
      for (int m = 0; m < 4; ++m) {
        const int R = m * 16 + (lane & 15);
        bf16x8 vf = *reinterpret_cast<const bf16x8*>(
            (const char*)&Vts[cur][0][0] + R * 128 + ((slot0 ^ (R & 7)) << 4));
        o[m] = __builtin_amdgcn_mfma_f32_16x16x32_bf16(vf, pf, o[m], 0, 0, 0);
      }
    }

    __syncthreads();   // drains prefetch; syncs buffer swap
    cur ^= 1;
  }

  // ---- epilogue: lane owns q=lane&15; d = m*16+g4e+r; packed 8B stores ----
  {
    const int q = lane & 15;
    const int g4e = (lane >> 4) << 2;
    const int srw = qb + w * 16 + q;
    const float inv = 1.0f / lrow;
#pragma unroll
    for (int m = 0; m < 4; ++m) {
      bf16x4 ov;
#pragma unroll
      for (int r = 0; r < 4; ++r) ov[r] = (bf16_t)(o[m][r] * inv);
      *reinterpret_cast<bf16x4*>(
          &AO[((size_t)(b * S_ + srw)) * 1024 + h * 64 + m * 16 + g4e]) = ov;
    }
  }
}

// ---------------- launch -----------------------------------------------------
extern "C" void kernel_launch(void* const* d_in, const int* in_sizes, int n_in,
                              void* d_out, int out_size, void* d_ws, size_t ws_size,
                              hipStream_t stream) {
  const float* x  = (const float*)d_in[0];
  const float* Wq = (const float*)d_in[1];
  const float* Wk = (const float*)d_in[2];
  const float* Wv = (const float*)d_in[3];
  const float* Wo = (const float*)d_in[4];
  const int* tp   = (const int*)d_in[5];

  char* ws = (char*)d_ws;
  bf16_t* xb   = (bf16_t*)(ws);               // 4096x1024      (8 MB)
  bf16_t* Wcat = (bf16_t*)(ws + 8388608);     // 3072x1024      (6 MB)
  bf16_t* Wob  = (bf16_t*)(ws + 14680064);    // 1024x1024      (2 MB)
  bf16_t* QKV  = (bf16_t*)(ws + 16777216);    // 4096x3072      (24 MB)
  bf16_t* Qr   = (bf16_t*)(ws + 41943040);    // (B,H,S,64)     (8 MB)
  bf16_t* Kr   = (bf16_t*)(ws + 50331648);    // (8 MB)
  bf16_t* Vt   = (bf16_t*)(ws + 58720256);    // (B,H,64,S)     (8 MB)
  bf16_t* AO   = (bf16_t*)(ws + 67108864);    // 4096x1024      (8 MB)

  cast_bf16_vec<<<dim3(4096), dim3(256), 0, stream>>>(x, xb, 1048576);
  cast_bf16_vec<<<dim3(1024), dim3(256), 0, stream>>>(Wq, Wcat, 262144);
  cast_bf16_vec<<<dim3(1024), dim3(256), 0, stream>>>(Wk, Wcat + 1048576, 262144);
  cast_bf16_vec<<<dim3(1024), dim3(256), 0, stream>>>(Wv, Wcat + 2097152, 262144);
  cast_bf16_vec<<<dim3(1024), dim3(256), 0, stream>>>(Wo, Wob, 262144);

  gemm_bt<false><<<dim3(32, 24), dim3(256), 0, stream>>>(xb, Wcat, (void*)QKV, 3072, 1024);
  rope_qk<<<dim3(8192), dim3(256), 0, stream>>>(QKV, tp, Qr, Kr);
  vtrans<<<dim3(32, 32), dim3(256), 0, stream>>>(QKV, Vt);
  attn_kernel<<<dim3(1024), dim3(256), 0, stream>>>(Qr, Kr, Vt, AO);
  gemm_bt<true><<<dim3(32, 8), dim3(256), 0, stream>>>(AO, Wob, d_out, 1024, 1024);

  (void)in_sizes; (void)n_in; (void)out_size; (void)ws_size;
}

// Round 8
// 136.636 us; speedup vs baseline: 1.9394x; 1.0691x over previous
//
#include <hip/hip_runtime.h>
#include <hip/hip_bf16.h>
#include <math.h>

#define B_ 2
#define S_ 2048
#define D_ 1024
#define H_ 16
#define DK_ 64

typedef __bf16 bf16_t;
typedef bf16_t bf16x8 __attribute__((ext_vector_type(8)));
typedef bf16_t bf16x4 __attribute__((ext_vector_type(4)));
typedef float f32x4 __attribute__((ext_vector_type(4)));

// async global->LDS, 16B per lane. LDS dest base must be wave-uniform; HW adds lane*16.
__device__ __forceinline__ void gload16(const void* g, void* lds_base_uniform) {
  __builtin_amdgcn_global_load_lds(
      (const __attribute__((address_space(1))) unsigned int*)g,
      (__attribute__((address_space(3))) unsigned int*)lds_base_uniform, 16, 0, 0);
}

// ---------------- cast fp32 -> bf16, vectorized ----------------
__global__ __launch_bounds__(256) void cast_bf16_vec(const float* __restrict__ in,
                                                     bf16_t* __restrict__ out, int n4) {
  int i = blockIdx.x * 256 + threadIdx.x;
  if (i >= n4) return;
  float4 f = reinterpret_cast<const float4*>(in)[i];
  bf16x4 o;
  o[0] = (bf16_t)f.x; o[1] = (bf16_t)f.y; o[2] = (bf16_t)f.z; o[3] = (bf16_t)f.w;
  reinterpret_cast<bf16x4*>(out)[i] = o;
}

// ---------------- generic GEMM (m97 structure), used for AO @ Wo^T ----------
template <bool OUT_F32>
__global__ __launch_bounds__(256) void gemm_bt(const bf16_t* __restrict__ A,
                                               const bf16_t* __restrict__ W,
                                               void* __restrict__ Cout,
                                               int Ndim, int Kdim) {
  __shared__ __attribute__((aligned(16))) bf16_t As[128][64];
  __shared__ __attribute__((aligned(16))) bf16_t Bs[128][64];
  const int bm = blockIdx.x * 128;
  const int bn = blockIdx.y * 128;
  const int tid = threadIdx.x;
  const int lane = tid & 63;
  const int w = tid >> 6;
  const int wr = w >> 1, wc = w & 1;
  const int srow_in_chunk = lane >> 3;
  const int scol = (lane & 7) << 3;

  f32x4 acc[4][4];
  for (int m = 0; m < 4; ++m)
    for (int n = 0; n < 4; ++n) acc[m][n] = (f32x4){0.f, 0.f, 0.f, 0.f};

  for (int k0 = 0; k0 < Kdim; k0 += 64) {
    __syncthreads();
#pragma unroll
    for (int it = 0; it < 4; ++it) {
      const int c = w * 4 + it;
      const int r = c * 8 + srow_in_chunk;
      gload16(&A[(size_t)(bm + r) * Kdim + k0 + scol], (char*)&As[0][0] + c * 1024);
      gload16(&W[(size_t)(bn + r) * Kdim + k0 + scol], (char*)&Bs[0][0] + c * 1024);
    }
    __syncthreads();
#pragma unroll
    for (int t = 0; t < 2; ++t) {
      const int kk = t * 32 + ((lane >> 4) << 3);
      bf16x8 af[4], bfr[4];
#pragma unroll
      for (int m = 0; m < 4; ++m)
        af[m] = *reinterpret_cast<const bf16x8*>(&As[wr * 64 + m * 16 + (lane & 15)][kk]);
#pragma unroll
      for (int n = 0; n < 4; ++n)
        bfr[n] = *reinterpret_cast<const bf16x8*>(&Bs[wc * 64 + n * 16 + (lane & 15)][kk]);
#pragma unroll
      for (int m = 0; m < 4; ++m)
#pragma unroll
        for (int n = 0; n < 4; ++n)
          acc[m][n] = __builtin_amdgcn_mfma_f32_16x16x32_bf16(af[m], bfr[n], acc[m][n], 0, 0, 0);
    }
  }

  const int rg = (lane >> 4) << 2, c0 = lane & 15;
#pragma unroll
  for (int m = 0; m < 4; ++m)
#pragma unroll
    for (int n = 0; n < 4; ++n) {
      int r = bm + wr * 64 + m * 16 + rg;
      int c = bn + wc * 64 + n * 16 + c0;
#pragma unroll
      for (int i = 0; i < 4; ++i) {
        if (OUT_F32)
          reinterpret_cast<float*>(Cout)[(size_t)(r + i) * Ndim + c] = acc[m][n][i];
        else
          reinterpret_cast<bf16_t*>(Cout)[(size_t)(r + i) * Ndim + c] = (bf16_t)acc[m][n][i];
      }
    }
}

// ---------------- fused QKV GEMM + RoPE + head reorder + V transpose --------
// C[4096, 3072] = xb @ Wcat^T. Each 128-col tile is entirely Q (bn<1024),
// K (1024..2047) or V (2048..3071) and covers exactly 2 heads.
// Epilogue bounces the C-tile through LDS (XOR 16B-slot swizzle, rule #21),
// applies RoPE (Q scaled 0.125) and writes Qr/Kr[bh][s][d] coalesced, or
// writes V transposed to Vt[bh][d][s] coalesced.
__global__ __launch_bounds__(256) void gemm_qkv(const bf16_t* __restrict__ A,
                                                const bf16_t* __restrict__ W,
                                                const int* __restrict__ posids,
                                                bf16_t* __restrict__ Qr,
                                                bf16_t* __restrict__ Kr,
                                                bf16_t* __restrict__ Vt) {
  __shared__ __attribute__((aligned(16))) bf16_t SMEM[2][128][64];
  const int bm = blockIdx.x * 128;
  const int bn = blockIdx.y * 128;
  const int tid = threadIdx.x;
  const int lane = tid & 63;
  const int w = tid >> 6;
  const int wr = w >> 1, wc = w & 1;
  const int srow_in_chunk = lane >> 3;
  const int scol = (lane & 7) << 3;
  const int Kdim = 1024;

  f32x4 acc[4][4];
  for (int m = 0; m < 4; ++m)
    for (int n = 0; n < 4; ++n) acc[m][n] = (f32x4){0.f, 0.f, 0.f, 0.f};

  for (int k0 = 0; k0 < Kdim; k0 += 64) {
    __syncthreads();
#pragma unroll
    for (int it = 0; it < 4; ++it) {
      const int c = w * 4 + it;
      const int r = c * 8 + srow_in_chunk;
      gload16(&A[(size_t)(bm + r) * Kdim + k0 + scol], (char*)&SMEM[0][0][0] + c * 1024);
      gload16(&W[(size_t)(bn + r) * Kdim + k0 + scol], (char*)&SMEM[1][0][0] + c * 1024);
    }
    __syncthreads();
#pragma unroll
    for (int t = 0; t < 2; ++t) {
      const int kk = t * 32 + ((lane >> 4) << 3);
      bf16x8 af[4], bfr[4];
#pragma unroll
      for (int m = 0; m < 4; ++m)
        af[m] = *reinterpret_cast<const bf16x8*>(&SMEM[0][wr * 64 + m * 16 + (lane & 15)][kk]);
#pragma unroll
      for (int n = 0; n < 4; ++n)
        bfr[n] = *reinterpret_cast<const bf16x8*>(&SMEM[1][wc * 64 + n * 16 + (lane & 15)][kk]);
#pragma unroll
      for (int m = 0; m < 4; ++m)
#pragma unroll
        for (int n = 0; n < 4; ++n)
          acc[m][n] = __builtin_amdgcn_mfma_f32_16x16x32_bf16(af[m], bfr[n], acc[m][n], 0, 0, 0);
    }
  }

  // ---- fused epilogue ----
  const int region = bn >> 10;            // 0=Q, 1=K, 2=V
  const int h0 = (bn & 1023) >> 6;        // first of the 2 heads in this tile
  const int b = bm >> 11;
  const int sblk = bm & 2047;
  char* Cs = (char*)&SMEM[0][0][0];       // 32KB contiguous C-tile bounce
  const int rg = (lane >> 4) << 2, c0 = lane & 15;

  __syncthreads();   // main-loop LDS reads complete before overwrite

  if (region < 2) {
    // normal orientation: Cs[row][col], byte = row*256 + ((col*2)^((row&15)<<4))
#pragma unroll
    for (int m = 0; m < 4; ++m)
#pragma unroll
      for (int n = 0; n < 4; ++n) {
        const int col = wc * 64 + n * 16 + c0;
#pragma unroll
        for (int i = 0; i < 4; ++i) {
          const int row = wr * 64 + m * 16 + rg + i;
          *(bf16_t*)(Cs + row * 256 + ((col * 2) ^ ((row & 15) << 4))) = (bf16_t)acc[m][n][i];
        }
      }
    __syncthreads();
    const int sl = tid >> 1;              // local s-row 0..127
    const int hh = tid & 1;               // which head-half (cols hh*64..)
    const int s = sblk + sl;
    const int bh = b * 16 + h0 + hh;
    const int p = posids[b * 2048 + s];
    bf16_t* outp = (region == 0 ? Qr : Kr) + ((size_t)bh * 2048 + s) * 64;
    const float qscale = region == 0 ? 0.125f : 1.0f;
#pragma unroll
    for (int j = 0; j < 8; ++j) {
      const int slot = hh * 8 + j;
      bf16x8 v = *(const bf16x8*)(Cs + sl * 256 + ((slot ^ (sl & 15)) << 4));
      bf16x8 ov;
#pragma unroll
      for (int e = 0; e < 8; e += 2) {
        const int ii = j * 4 + (e >> 1);  // pair index = d/2
        float sn, cs2;
        __sincosf((float)p * __expf(-(float)(2 * ii) * (9.210340371976184f / 64.0f)),
                  &sn, &cs2);
        const float x1 = (float)v[e], x2 = (float)v[e + 1];
        ov[e]     = (bf16_t)((cs2 * x1 - sn * x2) * qscale);
        ov[e + 1] = (bf16_t)((sn * x1 + cs2 * x2) * qscale);
      }
      *(bf16x8*)(&outp[j * 8]) = ov;
    }
  } else {
    // transposed: Cs_T[col][row], byte = col*256 + ((row*2)^((col&15)<<4));
    // fragment's 4 row-consecutive values pack into one 8B write.
#pragma unroll
    for (int m = 0; m < 4; ++m)
#pragma unroll
      for (int n = 0; n < 4; ++n) {
        const int col = wc * 64 + n * 16 + c0;
        const int row0 = wr * 64 + m * 16 + rg;
        bf16x4 pk;
#pragma unroll
        for (int i = 0; i < 4; ++i) pk[i] = (bf16_t)acc[m][n][i];
        *(bf16x4*)(Cs + col * 256 + ((row0 * 2) ^ ((col & 15) << 4))) = pk;
      }
    __syncthreads();
    const int dloc = tid >> 1;            // 0..127 (2 heads x 64)
    const int sg2 = tid & 1;              // s half (64 each)
    const int bh = b * 16 + h0 + (dloc >> 6);
    const int d = dloc & 63;
    bf16_t* outp = Vt + ((size_t)bh * 64 + d) * 2048 + sblk + sg2 * 64;
#pragma unroll
    for (int j = 0; j < 8; ++j) {
      bf16x8 v = *(const bf16x8*)(Cs + dloc * 256 + (((sg2 * 8 + j) ^ (dloc & 15)) << 4));
      *(bf16x8*)(&outp[j * 8]) = v;
    }
  }
}

// ---------------- causal flash attention (swapped-operand, per-lane q-row) ---
// grid: 1024 blocks, 256 threads (4 waves). Block = (bh = linear&31,
// qt = 31 - (linear>>5)) : LPT order, heavy supertiles dispatch first.
// Wave w owns q-rows [qt*64 + 16w, +16); lane owns q = lane&15.
__global__ __launch_bounds__(256) void attn_kernel(const bf16_t* __restrict__ Qr,
                                                   const bf16_t* __restrict__ Kr,
                                                   const bf16_t* __restrict__ Vt,
                                                   bf16_t* __restrict__ AO) {
  const int linear = blockIdx.x;
  const int bh = linear & 31;
  const int qt = 31 - (linear >> 5);
  const int b = bh >> 4, h = bh & 15;
  const bf16_t* Qp = Qr + (size_t)bh * S_ * 64;
  const char* Kbase = (const char*)(Kr + (size_t)bh * S_ * 64);
  const char* Vbase = (const char*)(Vt + (size_t)bh * 64 * S_);
  const int tid = threadIdx.x, lane = tid & 63, w = tid >> 6;
  const int qb = qt * 64;
  const int nt = qt + 1;

  __shared__ __attribute__((aligned(16))) bf16_t Ksm[2][64][64];
  __shared__ __attribute__((aligned(16))) bf16_t Vts[2][64][64];
  __shared__ __attribute__((aligned(16))) bf16_t Psm[4][16][72];

  const int srow = lane >> 3;
  const int sslot = lane & 7;

  bf16x8 qf[2];
  {
    int qrow = qb + w * 16 + (lane & 15);
#pragma unroll
    for (int t = 0; t < 2; ++t)
      qf[t] = *reinterpret_cast<const bf16x8*>(
          &Qp[(size_t)qrow * 64 + t * 32 + ((lane >> 4) << 3)]);
  }

  f32x4 o[4];
  for (int m = 0; m < 4; ++m) o[m] = (f32x4){0.f, 0.f, 0.f, 0.f};
  float mrow = -1e30f, lrow = 0.f;

#pragma unroll
  for (int it = 0; it < 2; ++it) {
    int c = 2 * w + it;
    int row = c * 8 + srow;
    gload16(Kbase + (size_t)row * 128 + ((sslot ^ (row & 7)) << 4),
            (char*)&Ksm[0][0][0] + c * 1024);
    gload16(Vbase + (size_t)row * (S_ * 2) + ((sslot ^ (row & 7)) << 4),
            (char*)&Vts[0][0][0] + c * 1024);
  }
  __syncthreads();

  int cur = 0;
#pragma unroll 1
  for (int kt = 0; kt < nt; ++kt) {
    if (kt + 1 < nt) {
#pragma unroll
      for (int it = 0; it < 2; ++it) {
        int c = 2 * w + it;
        int row = c * 8 + srow;
        gload16(Kbase + (size_t)(kt + 1) * 8192 + (size_t)row * 128 + ((sslot ^ (row & 7)) << 4),
                (char*)&Ksm[cur ^ 1][0][0] + c * 1024);
        gload16(Vbase + (size_t)row * (S_ * 2) + (size_t)(kt + 1) * 128 + ((sslot ^ (row & 7)) << 4),
                (char*)&Vts[cur ^ 1][0][0] + c * 1024);
      }
    }

    f32x4 sacc[4];
    for (int m = 0; m < 4; ++m) sacc[m] = (f32x4){0.f, 0.f, 0.f, 0.f};
#pragma unroll
    for (int t = 0; t < 2; ++t) {
      const int slot0 = t * 4 + (lane >> 4);
#pragma unroll
      for (int m = 0; m < 4; ++m) {
        const int R = m * 16 + (lane & 15);
        bf16x8 kfr = *reinterpret_cast<const bf16x8*>(
            (const char*)&Ksm[cur][0][0] + R * 128 + ((slot0 ^ (R & 7)) << 4));
        sacc[m] = __builtin_amdgcn_mfma_f32_16x16x32_bf16(kfr, qf[t], sacc[m], 0, 0, 0);
      }
    }

    const int qrow = qb + w * 16 + (lane & 15);
    const int g4 = (lane >> 4) << 2;
    if (kt * 64 + 63 > qb + w * 16) {
#pragma unroll
      for (int m = 0; m < 4; ++m) {
        const int kc0 = kt * 64 + m * 16 + g4;
#pragma unroll
        for (int r = 0; r < 4; ++r)
          if (kc0 + r > qrow) sacc[m][r] = -1e30f;
      }
    }

    float mx = sacc[0][0];
#pragma unroll
    for (int m = 0; m < 4; ++m)
#pragma unroll
      for (int r = 0; r < 4; ++r) mx = fmaxf(mx, sacc[m][r]);
    mx = fmaxf(mx, __shfl_xor(mx, 16, 64));
    mx = fmaxf(mx, __shfl_xor(mx, 32, 64));
    const float mnew = fmaxf(mrow, mx);
    const float alpha = __expf(mrow - mnew);
    mrow = mnew;

    float s = 0.f;
#pragma unroll
    for (int m = 0; m < 4; ++m)
#pragma unroll
      for (int r = 0; r < 4; ++r) {
        float p = __expf(sacc[m][r] - mnew);
        sacc[m][r] = p;
        s += p;
      }
    s += __shfl_xor(s, 16, 64);
    s += __shfl_xor(s, 32, 64);
    lrow = lrow * alpha + s;

#pragma unroll
    for (int m = 0; m < 4; ++m)
#pragma unroll
      for (int r = 0; r < 4; ++r) o[m][r] *= alpha;

    {
      const int q = lane & 15;
#pragma unroll
      for (int m = 0; m < 4; ++m) {
        bf16x4 pk;
#pragma unroll
        for (int r = 0; r < 4; ++r) pk[r] = (bf16_t)sacc[m][r];
        *reinterpret_cast<bf16x4*>(&Psm[w][q][m * 16 + g4]) = pk;
      }
    }

#pragma unroll
    for (int t = 0; t < 2; ++t) {
      const int kk = t * 32 + ((lane >> 4) << 3);
      const int slot0 = t * 4 + (lane >> 4);
      bf16x8 pf = *reinterpret_cast<const bf16x8*>(&Psm[w][lane & 15][kk]);
#pragma unroll
      for (int m = 0; m < 4; ++m) {
        const int R = m * 16 + (lane & 15);
        bf16x8 vf = *reinterpret_cast<const bf16x8*>(
            (const char*)&Vts[cur][0][0] + R * 128 + ((slot0 ^ (R & 7)) << 4));
        o[m] = __builtin_amdgcn_mfma_f32_16x16x32_bf16(vf, pf, o[m], 0, 0, 0);
      }
    }

    __syncthreads();
    cur ^= 1;
  }

  {
    const int q = lane & 15;
    const int g4e = (lane >> 4) << 2;
    const int srw = qb + w * 16 + q;
    const float inv = 1.0f / lrow;
#pragma unroll
    for (int m = 0; m < 4; ++m) {
      bf16x4 ov;
#pragma unroll
      for (int r = 0; r < 4; ++r) ov[r] = (bf16_t)(o[m][r] * inv);
      *reinterpret_cast<bf16x4*>(
          &AO[((size_t)(b * S_ + srw)) * 1024 + h * 64 + m * 16 + g4e]) = ov;
    }
  }
}

// ---------------- launch -----------------------------------------------------
extern "C" void kernel_launch(void* const* d_in, const int* in_sizes, int n_in,
                              void* d_out, int out_size, void* d_ws, size_t ws_size,
                              hipStream_t stream) {
  const float* x  = (const float*)d_in[0];
  const float* Wq = (const float*)d_in[1];
  const float* Wk = (const float*)d_in[2];
  const float* Wv = (const float*)d_in[3];
  const float* Wo = (const float*)d_in[4];
  const int* tp   = (const int*)d_in[5];

  char* ws = (char*)d_ws;
  bf16_t* xb   = (bf16_t*)(ws);               // 4096x1024      (8 MB)
  bf16_t* Wcat = (bf16_t*)(ws + 8388608);     // 3072x1024      (6 MB)
  bf16_t* Wob  = (bf16_t*)(ws + 14680064);    // 1024x1024      (2 MB)
  bf16_t* Qr   = (bf16_t*)(ws + 41943040);    // (B,H,S,64)     (8 MB)
  bf16_t* Kr   = (bf16_t*)(ws + 50331648);    // (8 MB)
  bf16_t* Vt   = (bf16_t*)(ws + 58720256);    // (B,H,64,S)     (8 MB)
  bf16_t* AO   = (bf16_t*)(ws + 67108864);    // 4096x1024      (8 MB)

  cast_bf16_vec<<<dim3(4096), dim3(256), 0, stream>>>(x, xb, 1048576);
  cast_bf16_vec<<<dim3(1024), dim3(256), 0, stream>>>(Wq, Wcat, 262144);
  cast_bf16_vec<<<dim3(1024), dim3(256), 0, stream>>>(Wk, Wcat + 1048576, 262144);
  cast_bf16_vec<<<dim3(1024), dim3(256), 0, stream>>>(Wv, Wcat + 2097152, 262144);
  cast_bf16_vec<<<dim3(1024), dim3(256), 0, stream>>>(Wo, Wob, 262144);

  gemm_qkv<<<dim3(32, 24), dim3(256), 0, stream>>>(xb, Wcat, tp, Qr, Kr, Vt);
  attn_kernel<<<dim3(1024), dim3(256), 0, stream>>>(Qr, Kr, Vt, AO);
  gemm_bt<true><<<dim3(32, 8), dim3(256), 0, stream>>>(AO, Wob, d_out, 1024, 1024);

  (void)in_sizes; (void)n_in; (void)out_size; (void)ws_size;
}